// Round 10
// baseline (154.118 us; speedup 1.0000x reference)
//
#include <hip/hip_runtime.h>
#include <math.h>

// Problem constants
#define BB   4
#define CC   128
#define HH   64
#define WW   64
#define OUTC 128
#define LW   5
#define KK   25   // LW*LW
#define NCS  16   // conv1 c-split count
#define CPER 8    // channels per split

typedef __attribute__((ext_vector_type(8))) short short8;   // 8 bf16
typedef __attribute__((ext_vector_type(4))) float floatx4;  // MFMA acc

__device__ __forceinline__ unsigned short f32_to_bf16(float v) {
    unsigned int u = __float_as_uint(v);
    u += 0x7fffu + ((u >> 16) & 1u);          // RNE
    return (unsigned short)(u >> 16);
}

// ---------------------------------------------------------------------------
// Kernel 0 (prep): two jobs in one launch.
//  i < 16384:  w2o[o][c] = bf16( sum_{r} w2[o, c*4+r] )      (o-major)
//  else:       w1t[kcg][c][kci][j] = w1[(kcg*5+kci)][c][j]   (45 contig / c)
// ---------------------------------------------------------------------------
__global__ void prep_kernel(const float* __restrict__ w2,
                            const float* __restrict__ w1,
                            unsigned short* __restrict__ w2o,
                            float* __restrict__ w1t) {
    int i = blockIdx.x * 256 + threadIdx.x;
    if (i < 16384) {
        int o = i >> 7, c = i & 127;
        const float* p = w2 + o * (4 * CC) + c * 4;
        w2o[o * CC + c] = f32_to_bf16(p[0] + p[1] + p[2] + p[3]);
    } else if (i < 16384 + 28800) {
        int j  = i - 16384;
        int jj = j % 9;
        int r  = j / 9;
        int kci = r % 5;  r /= 5;
        int c   = r % 128;
        int kcg = r / 128;
        w1t[j] = w1[(size_t)((kcg * 5 + kci) * CC + c) * 9 + jj];
    }
}

// ---------------------------------------------------------------------------
// Kernel 1: conv1 3x3 SAME. 4 px/thread (float4): per c-iter 180 FMA against
// 9 VMEM + 45 contiguous SMEM dwords -> compute dominates latency per iter.
// grid 4(b)*4(ht of 16 rows)*16(cs)*5(kcg) = 1280 blocks, 256 threads.
// Output: per-cs partial slabs kwsP[cs][b][kc][h][w].
// ---------------------------------------------------------------------------
__global__ __launch_bounds__(256, 4) void conv1_kernel(
        const float* __restrict__ x,
        const float* __restrict__ w1t,
        float* __restrict__ kwsP) {
    int bid = blockIdx.x;
    int kcg  = bid % 5;
    int rest = bid / 5;
    int cs   = rest & 15;
    rest >>= 4;
    int ht = rest & 3;
    int b  = rest >> 2;

    int t  = threadIdx.x;
    int w4 = t & 15;
    int r  = t >> 4;
    int h  = ht * 16 + r;
    int col0 = 4 * w4;

    float mt = (h > 0)        ? 1.f : 0.f;
    float mb = (h < HH - 1)   ? 1.f : 0.f;
    float ml = (col0 > 0)     ? 1.f : 0.f;
    float mr = (col0 + 4 < WW)? 1.f : 0.f;
    int y0 = (h > 0) ? h - 1 : 0;
    int y2 = (h < HH - 1) ? h + 1 : HH - 1;
    int cl = (col0 > 0) ? col0 - 1 : 0;
    int cr = (col0 + 4 < WW) ? col0 + 4 : WW - 1;

    float acc[5][4];
    #pragma unroll
    for (int k = 0; k < 5; ++k)
        { acc[k][0] = 0.f; acc[k][1] = 0.f; acc[k][2] = 0.f; acc[k][3] = 0.f; }

    const float* xb = x + ((size_t)b * CC + cs * CPER) * (HH * WW);
    const float* wb = w1t + ((size_t)kcg * CC + cs * CPER) * 45;

    #pragma unroll 2
    for (int c = 0; c < CPER; ++c) {
        const float* xc = xb + c * (HH * WW);
        const float* r0p = xc + y0 * WW;
        const float* r1p = xc + h  * WW;
        const float* r2p = xc + y2 * WW;

        float4 v0 = *(const float4*)(r0p + col0);
        float4 v1 = *(const float4*)(r1p + col0);
        float4 v2 = *(const float4*)(r2p + col0);
        float l0 = r0p[cl], l1 = r1p[cl], l2 = r2p[cl];
        float q0 = r0p[cr], q1 = r1p[cr], q2 = r2p[cr];

        v0.x *= mt; v0.y *= mt; v0.z *= mt; v0.w *= mt;
        l0 *= mt * ml; q0 *= mt * mr;
        l1 *= ml; q1 *= mr;
        v2.x *= mb; v2.y *= mb; v2.z *= mb; v2.w *= mb;
        l2 *= mb * ml; q2 *= mb * mr;

        const float* wc = wb + (size_t)c * 45;   // 45 contiguous dwords
        #pragma unroll
        for (int kci = 0; kci < 5; ++kci) {
            const float* wk = wc + kci * 9;
            float w0 = wk[0], w1v = wk[1], w2v = wk[2];
            float w3 = wk[3], w4v = wk[4], w5v = wk[5];
            float w6 = wk[6], w7v = wk[7], w8v = wk[8];
            acc[kci][0] += l0   * w0 + v0.x * w1v + v0.y * w2v
                         + l1   * w3 + v1.x * w4v + v1.y * w5v
                         + l2   * w6 + v2.x * w7v + v2.y * w8v;
            acc[kci][1] += v0.x * w0 + v0.y * w1v + v0.z * w2v
                         + v1.x * w3 + v1.y * w4v + v1.z * w5v
                         + v2.x * w6 + v2.y * w7v + v2.z * w8v;
            acc[kci][2] += v0.y * w0 + v0.z * w1v + v0.w * w2v
                         + v1.y * w3 + v1.z * w4v + v1.w * w5v
                         + v2.y * w6 + v2.z * w7v + v2.w * w8v;
            acc[kci][3] += v0.z * w0 + v0.w * w1v + q0   * w2v
                         + v1.z * w3 + v1.w * w4v + q1   * w5v
                         + v2.z * w6 + v2.w * w7v + q2   * w8v;
        }
    }

    float* kb = kwsP + ((size_t)(cs * BB + b) * KK + kcg * 5) * (HH * WW)
                     + h * WW + col0;
    #pragma unroll
    for (int kci = 0; kci < 5; ++kci)
        *(float4*)(kb + (size_t)kci * (HH * WW)) =
            make_float4(acc[kci][0], acc[kci][1], acc[kci][2], acc[kci][3]);
}

// ---------------------------------------------------------------------------
// Kernel 2: fused softmax (per-thread, in registers) + local attention +
//           MFMA GEMM (bf16) + 2x2-replicated write.
// 8-px blocks: grid 4(b)*64(h)*8(wq) = 2048 blocks of 256 threads.
// ---------------------------------------------------------------------------
__global__ __launch_bounds__(256, 4) void fused_kernel(
        const float* __restrict__ x,
        const unsigned short* __restrict__ w2o,
        const float* __restrict__ b1,
        const float* __restrict__ b2,
        const float* __restrict__ kwsP,
        float* __restrict__ out) {
    __shared__ float pk[KK * 8];                   // logits [k][px]  (800 B)
    __shared__ float xld[64 * 5 * 14];             // x tile          (17.9 KB)
    __shared__ unsigned short sKT[16 * 136];       // s bf16 [px][c]  (4.25 KB)

    int bid = blockIdx.x;
    int wq = bid & 7;
    int h  = (bid >> 3) & 63;
    int b  = bid >> 9;
    int t  = threadIdx.x;

    // ---- Phase 1: sum NCS conv1 partials + bias -> logits in pk ----
    const size_t sl = (size_t)BB * KK * HH * WW;
    if (t < KK * 8) {
        int kk = t >> 3, px = t & 7;
        size_t o0 = ((size_t)b * KK + kk) * (HH * WW) + h * WW + wq * 8 + px;
        float v = b1[kk];
        #pragma unroll
        for (int cs = 0; cs < NCS; ++cs) v += kwsP[o0 + cs * sl];
        pk[t] = v;
    }
    __syncthreads();

    // ---- per-thread softmax for pixel pair {2pp, 2pp+1} (registers) ----
    int pp = t & 3, cl = t >> 2;   // cl in 0..63
    float p0[KK], p1[KK];
    #pragma unroll
    for (int k = 0; k < KK; ++k) {
        float2 l = *(const float2*)&pk[k * 8 + 2 * pp];
        p0[k] = l.x; p1[k] = l.y;
    }
    float mx0 = -1e30f, mx1 = -1e30f;
    #pragma unroll
    for (int k = 0; k < KK; ++k) {
        mx0 = fmaxf(mx0, p0[k]); mx1 = fmaxf(mx1, p1[k]);
    }
    float s0 = 0.f, s1 = 0.f;
    #pragma unroll
    for (int k = 0; k < KK; ++k) {
        p0[k] = __expf(p0[k] - mx0); s0 += p0[k];
        p1[k] = __expf(p1[k] - mx1); s1 += p1[k];
    }
    float i0 = 1.f / s0, i1 = 1.f / s1;
    #pragma unroll
    for (int k = 0; k < KK; ++k) { p0[k] *= i0; p1[k] *= i1; }

    // ---- Phase 2: s[c][px] over 2 chunks of 64 channels ----
    const float* xb = x + (size_t)(b * CC) * (HH * WW);
    for (int ch = 0; ch < 2; ++ch) {
        __syncthreads();
        // stage 64 c x 5 rows x 12 cols (stride 14), float2-vectorized
        for (int i = t; i < 2240; i += 256) {      // float2 units
            int c   = i / 35;
            int rem = i - c * 35;
            int di  = rem / 7;
            int c2  = rem - di * 7;
            if (c2 < 6) {
                int y  = h + di - 2;
                int x0 = wq * 8 + 2 * c2 - 2;
                float2 v = make_float2(0.f, 0.f);
                if (y >= 0 && y < HH && x0 >= 0 && x0 < WW)
                    v = *(const float2*)(xb + (size_t)(ch * 64 + c) * (HH * WW)
                                         + y * WW + x0);
                *(float2*)&xld[c * 70 + di * 14 + 2 * c2] = v;
            }
        }
        __syncthreads();

        float a0 = 0.f, a1 = 0.f;
        const float* xr = &xld[cl * 70 + 2 * pp];
        #pragma unroll
        for (int di = 0; di < 5; ++di) {
            float2 x01 = *(const float2*)(xr + di * 14);
            float2 x23 = *(const float2*)(xr + di * 14 + 2);
            float2 x45 = *(const float2*)(xr + di * 14 + 4);
            a0 += p0[di*5+0] * x01.x + p0[di*5+1] * x01.y + p0[di*5+2] * x23.x
                + p0[di*5+3] * x23.y + p0[di*5+4] * x45.x;
            a1 += p1[di*5+0] * x01.y + p1[di*5+1] * x23.x + p1[di*5+2] * x23.y
                + p1[di*5+3] * x45.x + p1[di*5+4] * x45.y;
        }
        int c = ch * 64 + cl;
        sKT[(2 * pp) * 136 + c]     = f32_to_bf16(a0);
        sKT[(2 * pp + 1) * 136 + c] = f32_to_bf16(a1);
    }
    __syncthreads();

    // ---- Phase 3: MFMA. C[o][px] = sum_c W2s[o][c] * s[c][px] ----
    // (sKT rows 8..15 are stale garbage; it only contaminates D cols 8..15,
    //  which are never stored.)
    int lane = t & 63;
    int wv   = t >> 6;
    int fpx  = lane & 15;
    int quad = lane >> 4;

    floatx4 acc0 = {0.f, 0.f, 0.f, 0.f};
    floatx4 acc1 = {0.f, 0.f, 0.f, 0.f};
    #pragma unroll
    for (int ks = 0; ks < 4; ++ks) {
        short8 bfrag = *(const short8*)&sKT[fpx * 136 + ks * 32 + quad * 8];
        short8 a0f = *(const short8*)&w2o[(size_t)(wv * 32 + fpx) * CC
                                          + ks * 32 + quad * 8];
        short8 a1f = *(const short8*)&w2o[(size_t)(wv * 32 + 16 + fpx) * CC
                                          + ks * 32 + quad * 8];
        acc0 = __builtin_amdgcn_mfma_f32_16x16x32_bf16(a0f, bfrag, acc0, 0, 0, 0);
        acc1 = __builtin_amdgcn_mfma_f32_16x16x32_bf16(a1f, bfrag, acc1, 0, 0, 0);
    }

    // ---- epilogue: valid pixels are fpx < 8; 2x2-replicated float2 writes ----
    if (fpx < 8) {
        float* ob = out + (size_t)(b * OUTC) * (4 * HH * WW);
        int y0r  = 2 * h;
        int xcol = 2 * (wq * 8 + fpx);
        #pragma unroll
        for (int tile = 0; tile < 2; ++tile) {
            #pragma unroll
            for (int reg = 0; reg < 4; ++reg) {
                int o = wv * 32 + tile * 16 + quad * 4 + reg;
                float v = (tile ? acc1[reg] : acc0[reg]) + b2[o];
                float2 v2 = make_float2(v, v);
                float* r0 = ob + ((size_t)o * (2 * HH) + y0r) * (2 * WW) + xcol;
                *(float2*)(r0)          = v2;
                *(float2*)(r0 + 2 * WW) = v2;
            }
        }
    }
}

// ---------------------------------------------------------------------------
extern "C" void kernel_launch(void* const* d_in, const int* in_sizes, int n_in,
                              void* d_out, int out_size, void* d_ws, size_t ws_size,
                              hipStream_t stream) {
    const float* x  = (const float*)d_in[0];
    const float* w1 = (const float*)d_in[1];
    const float* b1 = (const float*)d_in[2];
    const float* w2 = (const float*)d_in[3];
    const float* b2 = (const float*)d_in[4];
    float* out = (float*)d_out;

    const size_t slab = (size_t)BB * KK * HH * WW;        // 409600 floats/cs
    float* kwsP = (float*)d_ws;                           // 16 slabs: 26.2 MB
    unsigned short* w2o = (unsigned short*)(kwsP + NCS * slab);    // 32 KB
    float* w1t = (float*)(w2o + (size_t)OUTC * CC);                // 115 KB

    prep_kernel<<<(16384 + 28800 + 255) / 256, 256, 0, stream>>>(w2, w1, w2o, w1t);
    conv1_kernel<<<BB * 4 * NCS * 5, 256, 0, stream>>>(x, w1t, kwsP);
    fused_kernel<<<BB * HH * 8, 256, 0, stream>>>(x, w2o, b1, b2, kwsP, out);
}

// Round 11
// 135.738 us; speedup vs baseline: 1.1354x; 1.1354x over previous
//
#include <hip/hip_runtime.h>
#include <math.h>

// Problem constants
#define BB   4
#define CC   128
#define HH   64
#define WW   64
#define OUTC 128
#define LW   5
#define KK   25   // LW*LW
#define NCS  8    // conv1 c-split count (atomic-reduced, no slabs)
#define CPER 16   // channels per split

typedef __attribute__((ext_vector_type(8))) short short8;   // 8 bf16
typedef __attribute__((ext_vector_type(4))) float floatx4;  // MFMA acc

__device__ __forceinline__ unsigned short f32_to_bf16(float v) {
    unsigned int u = __float_as_uint(v);
    u += 0x7fffu + ((u >> 16) & 1u);          // RNE
    return (unsigned short)(u >> 16);
}

// ---------------------------------------------------------------------------
// Kernel 0 (prep): two jobs in one launch.
//  i < 16384:  w2o[o][c] = bf16( sum_{r} w2[o, c*4+r] )      (o-major)
//  else:       w1t[kcg][c][kci][j] = w1[(kcg*5+kci)][c][j]   (45 contig / c)
// ---------------------------------------------------------------------------
__global__ void prep_kernel(const float* __restrict__ w2,
                            const float* __restrict__ w1,
                            unsigned short* __restrict__ w2o,
                            float* __restrict__ w1t) {
    int i = blockIdx.x * 256 + threadIdx.x;
    if (i < 16384) {
        int o = i >> 7, c = i & 127;
        const float* p = w2 + o * (4 * CC) + c * 4;
        w2o[o * CC + c] = f32_to_bf16(p[0] + p[1] + p[2] + p[3]);
    } else if (i < 16384 + 28800) {
        int j  = i - 16384;
        int jj = j % 9;
        int r  = j / 9;
        int kci = r % 5;  r /= 5;
        int c   = r % 128;
        int kcg = r / 128;
        w1t[j] = w1[(size_t)((kcg * 5 + kci) * CC + c) * 9 + jj];
    }
}

// ---------------------------------------------------------------------------
// Kernel 1: conv1 3x3 SAME. 2 px/thread; explicit next-c register prefetch;
// atomicAdd partials into ONE zeroed slab (1.6 MB hot in L2, no slab traffic).
// XCD swizzle: bid = kcg*256 + group so the 5 kcg-blocks sharing an x-window
// are stride-256 (== 0 mod 8) -> same XCD L2.
// grid 5*256 = 1280 blocks of 256 threads.
// ---------------------------------------------------------------------------
__global__ __launch_bounds__(256) void conv1_kernel(
        const float* __restrict__ x,
        const float* __restrict__ w1t,
        float* __restrict__ kws) {
    int bid = blockIdx.x;
    int kcg = bid >> 8;          // 0..4
    int g   = bid & 255;
    int cs  = g & 7;
    int ht  = (g >> 3) & 7;
    int b   = g >> 6;

    int t  = threadIdx.x;
    int w2i = t & 31;
    int r   = t >> 5;
    int h   = ht * 8 + r;
    int col0 = 2 * w2i;

    float mt = (h > 0)       ? 1.f : 0.f;
    float mb = (h < HH - 1)  ? 1.f : 0.f;
    float ml = (col0 > 0)    ? 1.f : 0.f;
    float mr = (col0 + 2 < WW) ? 1.f : 0.f;
    int y0 = (h > 0) ? h - 1 : 0;
    int y2 = (h < HH - 1) ? h + 1 : HH - 1;
    int cl = (col0 > 0) ? col0 - 1 : 0;
    int cr = (col0 + 2 < WW) ? col0 + 2 : WW - 1;

    float acc[5][2];
    #pragma unroll
    for (int k = 0; k < 5; ++k) { acc[k][0] = 0.f; acc[k][1] = 0.f; }

    const float* xb = x + ((size_t)b * CC + cs * CPER) * (HH * WW);
    const float* wb = w1t + ((size_t)kcg * CC + cs * CPER) * 45;

    // prologue: load c = 0
    float2 cv0 = *(const float2*)(xb + y0 * WW + col0);
    float2 cv1 = *(const float2*)(xb + h  * WW + col0);
    float2 cv2 = *(const float2*)(xb + y2 * WW + col0);
    float cl0 = xb[y0 * WW + cl], cl1 = xb[h * WW + cl], cl2 = xb[y2 * WW + cl];
    float cq0 = xb[y0 * WW + cr], cq1 = xb[h * WW + cr], cq2 = xb[y2 * WW + cr];

    #pragma unroll 4
    for (int c = 0; c < CPER; ++c) {
        // prefetch next channel's 9 values before consuming current
        float2 nv0, nv1, nv2;
        float nl0 = 0.f, nl1 = 0.f, nl2 = 0.f, nq0 = 0.f, nq1 = 0.f, nq2 = 0.f;
        if (c + 1 < CPER) {
            const float* xn = xb + (size_t)(c + 1) * (HH * WW);
            nv0 = *(const float2*)(xn + y0 * WW + col0);
            nv1 = *(const float2*)(xn + h  * WW + col0);
            nv2 = *(const float2*)(xn + y2 * WW + col0);
            nl0 = xn[y0 * WW + cl]; nl1 = xn[h * WW + cl]; nl2 = xn[y2 * WW + cl];
            nq0 = xn[y0 * WW + cr]; nq1 = xn[h * WW + cr]; nq2 = xn[y2 * WW + cr];
        } else {
            nv0 = make_float2(0.f, 0.f); nv1 = nv0; nv2 = nv0;
        }

        // apply boundary masks to current values
        float a0x = cv0.x * mt, a0y = cv0.y * mt;
        float a2x = cv2.x * mb, a2y = cv2.y * mb;
        float al0 = cl0 * mt * ml, aq0 = cq0 * mt * mr;
        float al1 = cl1 * ml,      aq1 = cq1 * mr;
        float al2 = cl2 * mb * ml, aq2 = cq2 * mb * mr;

        const float* wc = wb + (size_t)c * 45;   // 45 contiguous dwords
        #pragma unroll
        for (int kci = 0; kci < 5; ++kci) {
            const float* wk = wc + kci * 9;
            float w0 = wk[0], w1v = wk[1], w2v = wk[2];
            float w3 = wk[3], w4v = wk[4], w5v = wk[5];
            float w6 = wk[6], w7v = wk[7], w8v = wk[8];
            acc[kci][0] += al0   * w0 + a0x   * w1v + a0y   * w2v
                         + al1   * w3 + cv1.x * w4v + cv1.y * w5v
                         + al2   * w6 + a2x   * w7v + a2y   * w8v;
            acc[kci][1] += a0x   * w0 + a0y   * w1v + aq0   * w2v
                         + cv1.x * w3 + cv1.y * w4v + aq1   * w5v
                         + a2x   * w6 + a2y   * w7v + aq2   * w8v;
        }

        cv0 = nv0; cv1 = nv1; cv2 = nv2;
        cl0 = nl0; cl1 = nl1; cl2 = nl2;
        cq0 = nq0; cq1 = nq1; cq2 = nq2;
    }

    float* kb = kws + ((size_t)b * KK + kcg * 5) * (HH * WW) + h * WW + col0;
    #pragma unroll
    for (int kci = 0; kci < 5; ++kci) {
        atomicAdd(kb + (size_t)kci * (HH * WW),     acc[kci][0]);
        atomicAdd(kb + (size_t)kci * (HH * WW) + 1, acc[kci][1]);
    }
}

// ---------------------------------------------------------------------------
// Kernel 2: fused softmax (per-thread registers) + local attention +
//           MFMA GEMM (bf16) + 2x2-replicated write.
// Block = 16 px (2 rows x 8 cols): grid 4(b)*32(hb)*8(wq) = 1024 blocks.
// wq in low bits -> h-neighbors (sharing x rows) on the same XCD.
// ---------------------------------------------------------------------------
__global__ __launch_bounds__(256) void fused_kernel(
        const float* __restrict__ x,
        const unsigned short* __restrict__ w2o,
        const float* __restrict__ b1,
        const float* __restrict__ b2,
        const float* __restrict__ kws,
        float* __restrict__ out) {
    __shared__ float pk[KK * 16];                  // logits [k][px]  (1.6 KB)
    __shared__ float xld[64 * 76];                 // x tile, 64c x 6r x 12+4pad (19.5 KB)
    __shared__ unsigned short sKT[16 * 136];       // s bf16 [px][c]  (4.25 KB)

    int bid = blockIdx.x;
    int wq = bid & 7;
    int hb = (bid >> 3) & 31;
    int b  = bid >> 8;
    int t  = threadIdx.x;

    // ---- Phase 1: read conv1 logits (single slab) + bias ----
    for (int i = t; i < KK * 16; i += 256) {
        int kk = i >> 4, px = i & 15;
        int y  = 2 * hb + (px >> 3);
        int xc = wq * 8 + (px & 7);
        pk[i] = kws[((size_t)b * KK + kk) * (HH * WW) + y * WW + xc] + b1[kk];
    }
    __syncthreads();

    // ---- per-thread softmax for px pair {2pp, 2pp+1} (same row) ----
    int pp = t & 7, cl = t >> 3;   // cl in 0..31 (c-lane)
    int px0 = 2 * pp;              // row = px0>>3, col0 = px0&7 (even)
    float p0[KK], p1[KK];
    #pragma unroll
    for (int k = 0; k < KK; ++k) {
        float2 l = *(const float2*)&pk[k * 16 + px0];
        p0[k] = l.x; p1[k] = l.y;
    }
    float mx0 = -1e30f, mx1 = -1e30f;
    #pragma unroll
    for (int k = 0; k < KK; ++k) {
        mx0 = fmaxf(mx0, p0[k]); mx1 = fmaxf(mx1, p1[k]);
    }
    float s0 = 0.f, s1 = 0.f;
    #pragma unroll
    for (int k = 0; k < KK; ++k) {
        p0[k] = __expf(p0[k] - mx0); s0 += p0[k];
        p1[k] = __expf(p1[k] - mx1); s1 += p1[k];
    }
    float i0 = 1.f / s0, i1 = 1.f / s1;
    #pragma unroll
    for (int k = 0; k < KK; ++k) { p0[k] *= i0; p1[k] *= i1; }

    int prow = px0 >> 3, pcol = px0 & 7;

    // ---- Phase 2: s[c][px] over 2 chunks of 64 channels ----
    const float* xb = x + (size_t)(b * CC) * (HH * WW);
    for (int ch = 0; ch < 2; ++ch) {
        __syncthreads();
        // stage 64 c x 6 rows x 12 cols (stride 76/c), float2-vectorized
        for (int i = t; i < 2304; i += 256) {
            int c   = i / 36;
            int rem = i - c * 36;
            int di  = rem / 6;
            int c2  = rem - di * 6;
            int y   = 2 * hb - 2 + di;
            int x0  = wq * 8 + 2 * c2 - 2;
            float2 v = make_float2(0.f, 0.f);
            if (y >= 0 && y < HH && x0 >= 0 && x0 <= WW - 2)
                v = *(const float2*)(xb + (size_t)(ch * 64 + c) * (HH * WW)
                                     + y * WW + x0);
            *(float2*)&xld[c * 76 + di * 12 + 2 * c2] = v;
        }
        __syncthreads();

        #pragma unroll
        for (int j = 0; j < 2; ++j) {          // 2 channels per thread
            int c = cl * 2 + j;
            float a0 = 0.f, a1 = 0.f;
            const float* xr = &xld[c * 76 + prow * 12 + pcol];
            #pragma unroll
            for (int di = 0; di < 5; ++di) {
                float2 x01 = *(const float2*)(xr + di * 12);
                float2 x23 = *(const float2*)(xr + di * 12 + 2);
                float2 x45 = *(const float2*)(xr + di * 12 + 4);
                a0 += p0[di*5+0] * x01.x + p0[di*5+1] * x01.y + p0[di*5+2] * x23.x
                    + p0[di*5+3] * x23.y + p0[di*5+4] * x45.x;
                a1 += p1[di*5+0] * x01.y + p1[di*5+1] * x23.x + p1[di*5+2] * x23.y
                    + p1[di*5+3] * x45.x + p1[di*5+4] * x45.y;
            }
            int cg = ch * 64 + c;
            sKT[px0 * 136 + cg]       = f32_to_bf16(a0);
            sKT[(px0 + 1) * 136 + cg] = f32_to_bf16(a1);
        }
    }
    __syncthreads();

    // ---- Phase 3: MFMA. C[o][px] = sum_c W2s[o][c] * s[c][px] ----
    int lane = t & 63;
    int wv   = t >> 6;
    int fpx  = lane & 15;
    int quad = lane >> 4;

    floatx4 acc0 = {0.f, 0.f, 0.f, 0.f};
    floatx4 acc1 = {0.f, 0.f, 0.f, 0.f};
    #pragma unroll
    for (int ks = 0; ks < 4; ++ks) {
        short8 bfrag = *(const short8*)&sKT[fpx * 136 + ks * 32 + quad * 8];
        short8 a0f = *(const short8*)&w2o[(size_t)(wv * 32 + fpx) * CC
                                          + ks * 32 + quad * 8];
        short8 a1f = *(const short8*)&w2o[(size_t)(wv * 32 + 16 + fpx) * CC
                                          + ks * 32 + quad * 8];
        acc0 = __builtin_amdgcn_mfma_f32_16x16x32_bf16(a0f, bfrag, acc0, 0, 0, 0);
        acc1 = __builtin_amdgcn_mfma_f32_16x16x32_bf16(a1f, bfrag, acc1, 0, 0, 0);
    }

    // ---- epilogue: all 16 px valid; 2x2-replicated float2 writes ----
    float* ob = out + (size_t)(b * OUTC) * (4 * HH * WW);
    int y0r  = 2 * (2 * hb + (fpx >> 3));
    int xcol = 2 * (wq * 8 + (fpx & 7));
    #pragma unroll
    for (int tile = 0; tile < 2; ++tile) {
        float4 bv = *(const float4*)(b2 + wv * 32 + tile * 16 + quad * 4);
        #pragma unroll
        for (int reg = 0; reg < 4; ++reg) {
            int o = wv * 32 + tile * 16 + quad * 4 + reg;
            float v = (tile ? acc1[reg] : acc0[reg])
                    + ((const float*)&bv)[reg];
            float2 v2 = make_float2(v, v);
            float* r0 = ob + ((size_t)o * (2 * HH) + y0r) * (2 * WW) + xcol;
            *(float2*)(r0)          = v2;
            *(float2*)(r0 + 2 * WW) = v2;
        }
    }
}

// ---------------------------------------------------------------------------
extern "C" void kernel_launch(void* const* d_in, const int* in_sizes, int n_in,
                              void* d_out, int out_size, void* d_ws, size_t ws_size,
                              hipStream_t stream) {
    const float* x  = (const float*)d_in[0];
    const float* w1 = (const float*)d_in[1];
    const float* b1 = (const float*)d_in[2];
    const float* w2 = (const float*)d_in[3];
    const float* b2 = (const float*)d_in[4];
    float* out = (float*)d_out;

    const size_t slab = (size_t)BB * KK * HH * WW;        // 409600 floats
    float* kws = (float*)d_ws;                            // 1.6 MB (atomic)
    unsigned short* w2o = (unsigned short*)(kws + slab);  // 32 KB
    float* w1t = (float*)(w2o + (size_t)OUTC * CC);       // 115 KB

    hipMemsetAsync(kws, 0, slab * sizeof(float), stream);
    prep_kernel<<<(16384 + 28800 + 255) / 256, 256, 0, stream>>>(w2, w1, w2o, w1t);
    conv1_kernel<<<5 * 256, 256, 0, stream>>>(x, w1t, kws);
    fused_kernel<<<BB * 32 * 8, 256, 0, stream>>>(x, w2o, b1, b2, kws, out);
}